// Round 18
// baseline (105.181 us; speedup 1.0000x reference)
//
#include <hip/hip_runtime.h>
#include <hip/hip_bf16.h>
#include <stdint.h>

typedef __bf16 bf16x8 __attribute__((ext_vector_type(8)));
typedef float  f32x4  __attribute__((ext_vector_type(4)));

#define B_   2
#define T_   2048
#define H_   16
#define DH_  64
#define DM_  1024
#define BH_  (B_*H_)   // 32
#define M_   (B_*T_)   // 4096

#define QSCALE 0.18033688f   // 1/sqrt(64) * log2(e), folded into Q
#define FIXED_M 8.0f         // static softmax max (exp2 domain)

#define SBAR() __builtin_amdgcn_sched_barrier(0)

// ---- async global->LDS, 16B per lane; LDS dest must be wave-uniform base ----
static __device__ __forceinline__ void gload_lds16(const void* g, void* lds) {
  __builtin_amdgcn_global_load_lds(
      (const __attribute__((address_space(1))) void*)(uintptr_t)g,
      (__attribute__((address_space(3))) void*)(uint32_t)(uintptr_t)lds,
      16, 0, 0);
}

// ---------------- fused prep: cvt x + transpose both weights ----------------
__global__ void k_prep(const float* __restrict__ x, const float* __restrict__ wqkv,
                       const float* __restrict__ wout, __hip_bfloat16* __restrict__ xb,
                       __hip_bfloat16* __restrict__ wqkvT, __hip_bfloat16* __restrict__ woutT) {
  __shared__ float tile[32][33];
  const int bid = blockIdx.x, tid = threadIdx.x;
  if (bid < 4096) {
    int i = bid * 256 + tid;                       // 1M float4 = all of x
    float4 v = reinterpret_cast<const float4*>(x)[i];
    alignas(8) __hip_bfloat16 t[4] = {__float2bfloat16(v.x), __float2bfloat16(v.y),
                                      __float2bfloat16(v.z), __float2bfloat16(v.w)};
    reinterpret_cast<uint2*>(xb)[i] = *reinterpret_cast<const uint2*>(t);
    return;
  }
  const float* in; __hip_bfloat16* out; int K, N, n0, k0;
  if (bid < 7168) {
    int t = bid - 4096; in = wqkv; out = wqkvT; K = 1024; N = 3072;
    n0 = (t % 96) * 32; k0 = (t / 96) * 32;
  } else {
    int t = bid - 7168; in = wout; out = woutT; K = 1024; N = 1024;
    n0 = (t % 32) * 32; k0 = (t / 32) * 32;
  }
  int kl = tid >> 3, n4 = (tid & 7) * 4;
  float4 v = *reinterpret_cast<const float4*>(in + (size_t)(k0 + kl) * N + n0 + n4);
  tile[kl][n4 + 0] = v.x; tile[kl][n4 + 1] = v.y; tile[kl][n4 + 2] = v.z; tile[kl][n4 + 3] = v.w;
  __syncthreads();
  int nl = tid >> 3, k4 = (tid & 7) * 4;
  alignas(8) __hip_bfloat16 t[4];
  #pragma unroll
  for (int j = 0; j < 4; ++j) t[j] = __float2bfloat16(tile[k4 + j][nl]);
  *reinterpret_cast<uint2*>(out + (size_t)(n0 + nl) * K + k0 + k4) = *reinterpret_cast<const uint2*>(t);
}

// ---- pipelined bf16 GEMM core (B^T input), BK=32, 4 waves, 3-slot ring ----
template<int BM, int BN, int FM, int FN>
static __device__ __forceinline__ void gemm_core_pipe(
    const __hip_bfloat16* __restrict__ A, const __hip_bfloat16* __restrict__ BT,
    int K, int brow, int bcol, __hip_bfloat16* As, __hip_bfloat16* Bs,
    f32x4 acc[FM][FN]) {
  constexpr int WGN = BN / (16 * FN);
  constexpr int LOADS = BM / 64 + BN / 64;       // gloads per wave per stage
  constexpr int ASLOT = BM * 32, BSLOT = BN * 32;
  const int tid = threadIdx.x, wave = tid >> 6, lane = tid & 63;
  const int wr = wave / WGN, wc = wave % WGN;
  const int llo = lane & 15, lhi = lane >> 4;
  const int nk = K / 32;
  const int schunk = (lane & 3) ^ ((lane >> 3) & 3);
  auto stage = [&](int ks, int slot) {
    #pragma unroll
    for (int c = wave; c < BM / 16; c += 4)
      gload_lds16(A + (size_t)(brow + c * 16 + (lane >> 2)) * K + ks * 32 + schunk * 8,
                  As + slot * ASLOT + c * 512);
    #pragma unroll
    for (int c = wave; c < BN / 16; c += 4)
      gload_lds16(BT + (size_t)(bcol + c * 16 + (lane >> 2)) * K + ks * 32 + schunk * 8,
                  Bs + slot * BSLOT + c * 512);
  };
  stage(0, 0);
  stage(1, 1);
  const int rchunk = lhi ^ ((llo >> 1) & 3);     // swizzled read chunk
  for (int ks = 0; ks < nk; ++ks) {
    if constexpr (LOADS == 4)      asm volatile("s_waitcnt vmcnt(4)" ::: "memory");
    else if constexpr (LOADS == 3) asm volatile("s_waitcnt vmcnt(3)" ::: "memory");
    else                           asm volatile("s_waitcnt vmcnt(0)" ::: "memory");
    SBAR();
    __builtin_amdgcn_s_barrier();
    SBAR();
    const int s2 = (ks + 2 < nk) ? ks + 2 : nk - 1;  // clamped redundant tail
    stage(s2, (ks + 2) % 3);
    const __hip_bfloat16* Asl = As + (ks % 3) * ASLOT;
    const __hip_bfloat16* Bsl = Bs + (ks % 3) * BSLOT;
    bf16x8 a[FM], b[FN];
    #pragma unroll
    for (int i = 0; i < FM; ++i)
      a[i] = *reinterpret_cast<const bf16x8*>(
          Asl + (wr * FM * 16 + i * 16 + llo) * 32 + rchunk * 8);
    #pragma unroll
    for (int j = 0; j < FN; ++j)
      b[j] = *reinterpret_cast<const bf16x8*>(
          Bsl + (wc * FN * 16 + j * 16 + llo) * 32 + rchunk * 8);
    __builtin_amdgcn_s_setprio(1);
    #pragma unroll
    for (int i = 0; i < FM; ++i)
      #pragma unroll
      for (int j = 0; j < FN; ++j)
        acc[i][j] = __builtin_amdgcn_mfma_f32_16x16x32_bf16(a[i], b[j], acc[i][j], 0, 0, 0);
    __builtin_amdgcn_s_setprio(0);
  }
  asm volatile("s_waitcnt vmcnt(0)" ::: "memory");
}

// GEMM1: qkv = xb @ w_qkv (128x128 tile, proven core, 2D grid).
__global__ __launch_bounds__(256) void k_gemm_qkv(
    const __hip_bfloat16* __restrict__ A, const __hip_bfloat16* __restrict__ BT,
    __hip_bfloat16* __restrict__ q_ws, __hip_bfloat16* __restrict__ k_ws,
    __hip_bfloat16* __restrict__ vT) {
  alignas(16) __shared__ __hip_bfloat16 As[3 * 128 * 32];
  alignas(16) __shared__ __hip_bfloat16 Bs[3 * 128 * 32];
  f32x4 acc[4][4] = {};
  const int brow = blockIdx.y * 128, bcol = blockIdx.x * 128;
  gemm_core_pipe<128, 128, 4, 4>(A, BT, DM_, brow, bcol, As, Bs, acc);
  const int tid = threadIdx.x, wave = tid >> 6, lane = tid & 63;
  const int wr = wave >> 1, wc = wave & 1;
  const int llo = lane & 15, lhi = lane >> 4;
  #pragma unroll
  for (int i = 0; i < 4; ++i) {
    const int tbase = brow + wr * 64 + i * 16 + lhi * 4;  // 4 consecutive t
    const int b = tbase >> 11, t = tbase & 2047;
    #pragma unroll
    for (int j = 0; j < 4; ++j) {
      int n = bcol + wc * 64 + j * 16 + llo;
      int part = n >> 10, rem = n & 1023, hh = rem >> 6, dh = rem & 63;
      if (part == 2) {
        alignas(8) __hip_bfloat16 tv[4];
        #pragma unroll
        for (int r = 0; r < 4; ++r) tv[r] = __float2bfloat16(acc[i][j][r]);
        *reinterpret_cast<uint2*>(
            vT + (((size_t)(b * H_ + hh)) * DH_ + dh) * T_ + t) =
            *reinterpret_cast<const uint2*>(tv);
      } else {
        float sc = (part == 0) ? QSCALE : 1.0f;   // fold softmax scale into Q
        __hip_bfloat16* dst = (part == 0) ? q_ws : k_ws;
        #pragma unroll
        for (int r = 0; r < 4; ++r)
          dst[(((size_t)(b * H_ + hh)) * T_ + t + r) * DH_ + dh] =
              __float2bfloat16(acc[i][j][r] * sc);
      }
    }
  }
}

// GEMM2: out = y @ w_out (f32 output). 128x64 tile -> 512 blocks (2/CU).
__global__ __launch_bounds__(256) void k_gemm_out(
    const __hip_bfloat16* __restrict__ A, const __hip_bfloat16* __restrict__ BT,
    float* __restrict__ C) {
  alignas(16) __shared__ __hip_bfloat16 As[3 * 128 * 32];
  alignas(16) __shared__ __hip_bfloat16 Bs[3 * 64 * 32];
  f32x4 acc[4][2] = {};
  const int brow = blockIdx.y * 128, bcol = blockIdx.x * 64;
  gemm_core_pipe<128, 64, 4, 2>(A, BT, DM_, brow, bcol, As, Bs, acc);
  const int tid = threadIdx.x, wave = tid >> 6, lane = tid & 63;
  const int wr = wave >> 1, wc = wave & 1;
  const int llo = lane & 15, lhi = lane >> 4;
  #pragma unroll
  for (int i = 0; i < 4; ++i)
    #pragma unroll
    for (int j = 0; j < 2; ++j) {
      int n = bcol + wc * 32 + j * 16 + llo;
      #pragma unroll
      for (int r = 0; r < 4; ++r) {
        int m = brow + wr * 64 + i * 16 + lhi * 4 + r;
        C[(size_t)m * DM_ + n] = acc[i][j][r];
      }
    }
}

// ---------------- flash attention (causal), v13 ----------------
// Swapped-operand (r13-proven) + dual q-tile per WAVE: block = 4 waves
// (256 thr), grid (16, BH) = 512 blocks. Each wave owns 16 rows of BOTH
// q-tiles {qt_hi = 31-p, qt_lo = p} (named *_hi / *_lo state only — no
// runtime selection, rule #20). Each 8-read K-fragment set feeds 16 QK MFMAs
// (K-frag is the shared A-operand; aq_hi/aq_lo are register B-operands);
// 8 V-frag reads held in regs feed both PV phases. LDS reads per 32 q-rows:
// 36 -> 20. Control flow fully block-uniform (lo guarded by it <= p) ->
// zero barrier idling (v6 wasted 33% of wave-slots). 2-slot ring + single
// __syncthreads; LDS 40KB -> 3-4 blocks/CU. TBAA fences around every Ps
// pack<->read transition (shared Ps buffer reused hi then lo within iter).
__global__ __launch_bounds__(256) void k_attn(
    const __hip_bfloat16* __restrict__ Q, const __hip_bfloat16* __restrict__ Kk,
    const __hip_bfloat16* __restrict__ VT, __hip_bfloat16* __restrict__ Y) {
  alignas(16) __shared__ __hip_bfloat16 Ks[2][64 * 64];
  alignas(16) __shared__ __hip_bfloat16 Vs[2][64 * 64];   // [dh][t'] swizzled
  alignas(16) __shared__ __hip_bfloat16 Ps[4][16 * 64];
  const int bh = blockIdx.y;
  const int p  = blockIdx.x;                 // 0..15
  const int tid = threadIdx.x, wave = tid >> 6, lane = tid & 63;
  const int llo = lane & 15, lhi = lane >> 4;
  const int ntA = 32 - p;                    // loop length (>= 17)
  const int qhi0 = (31 - p) * 64, qlo0 = p * 64;
  const int myq_hi = qhi0 + wave * 16 + llo; // lane's q row, high tile
  const int myq_lo = qlo0 + wave * 16 + llo; // lane's q row, low tile

  const __hip_bfloat16* kb = Kk + (size_t)bh * T_ * DH_;
  const __hip_bfloat16* vb = VT + (size_t)bh * DH_ * T_;

  const int srow = lane >> 3;                // 0..7
  const int schunk = (lane & 7) ^ srow;      // involution XOR
  const int rb = wave * 16;                  // wave stages rows rb..rb+15

  bf16x8 aq_hi[2], aq_lo[2];
  #pragma unroll
  for (int k0 = 0; k0 < 2; ++k0) {
    aq_hi[k0] = *reinterpret_cast<const bf16x8*>(
        Q + ((size_t)bh * T_ + myq_hi) * DH_ + k0 * 32 + lhi * 8);
    aq_lo[k0] = *reinterpret_cast<const bf16x8*>(
        Q + ((size_t)bh * T_ + myq_lo) * DH_ + k0 * 32 + lhi * 8);
  }

  float lsum_hi = 0.f, lsum_lo = 0.f;
  f32x4 o_hi[4] = {}, o_lo[4] = {};

  // staging: wave covers 16 rows of K and 16 rows of V^T (4 gloads)
  auto stage = [&](int tile, int slot) {
    #pragma unroll
    for (int g = 0; g < 2; ++g) {
      const int row = rb + g * 8;
      gload_lds16(kb + (size_t)(tile * 64 + row + srow) * DH_ + schunk * 8,
                  &Ks[slot][row * 64]);
      gload_lds16(vb + (size_t)(row + srow) * T_ + tile * 64 + schunk * 8,
                  &Vs[slot][row * 64]);
    }
  };

  stage(0, 0);
  __syncthreads();

  char* psw = reinterpret_cast<char*>(&Ps[wave][0]);

  for (int it = 0; it < ntA; ++it) {
    const int cur = it & 1;
    if (it + 1 < ntA) stage(it + 1, cur ^ 1);   // issue next stage first
    const __hip_bfloat16* ksb = Ks[cur];
    const __hip_bfloat16* vsb = Vs[cur];
    const bool actlo = (it <= p);               // block-uniform guard

    // ---- QK^T: 8 K-frag reads feed up to 16 MFMA (hi + lo) ----
    f32x4 shi[4], slo[4];
    __builtin_amdgcn_s_setprio(1);
    #pragma unroll
    for (int jn = 0; jn < 4; ++jn) {
      const __hip_bfloat16* krow = ksb + (jn * 16 + llo) * 64;
      bf16x8 b0 = *reinterpret_cast<const bf16x8*>(krow + ((lhi ^ (llo & 7)) << 3));
      bf16x8 b1 = *reinterpret_cast<const bf16x8*>(krow + (((4 + lhi) ^ (llo & 7)) << 3));
      f32x4 z = {};
      z = __builtin_amdgcn_mfma_f32_16x16x32_bf16(b0, aq_hi[0], z, 0, 0, 0);
      z = __builtin_amdgcn_mfma_f32_16x16x32_bf16(b1, aq_hi[1], z, 0, 0, 0);
      shi[jn] = z;
      if (actlo) {
        f32x4 w = {};
        w = __builtin_amdgcn_mfma_f32_16x16x32_bf16(b0, aq_lo[0], w, 0, 0, 0);
        w = __builtin_amdgcn_mfma_f32_16x16x32_bf16(b1, aq_lo[1], w, 0, 0, 0);
        slo[jn] = w;
      }
    }
    __builtin_amdgcn_s_setprio(0);
    // causal mask: hi only on its diagonal (= last) iter; lo at it == p
    if (it == ntA - 1) {
      #pragma unroll
      for (int jn = 0; jn < 4; ++jn)
        #pragma unroll
        for (int r = 0; r < 4; ++r) {
          int tprime = qhi0 + jn * 16 + lhi * 4 + r;
          if (tprime > myq_hi) shi[jn][r] = -INFINITY;
        }
    }
    if (actlo && it == p) {
      #pragma unroll
      for (int jn = 0; jn < 4; ++jn)
        #pragma unroll
        for (int r = 0; r < 4; ++r) {
          int tprime = qlo0 + jn * 16 + lhi * 4 + r;
          if (tprime > myq_lo) slo[jn][r] = -INFINITY;
        }
    }
    // ---- V fragments once into regs (shared by both PV phases) ----
    bf16x8 vf0[4], vf1[4];
    #pragma unroll
    for (int jd = 0; jd < 4; ++jd) {
      const __hip_bfloat16* vrow = vsb + (jd * 16 + llo) * 64;
      vf0[jd] = *reinterpret_cast<const bf16x8*>(vrow + ((lhi ^ (llo & 7)) << 3));
      vf1[jd] = *reinterpret_cast<const bf16x8*>(vrow + (((4 + lhi) ^ (llo & 7)) << 3));
    }
    // ---- hi: softmax + pack + PV ----
    #pragma unroll
    for (int jn = 0; jn < 4; ++jn) {
      float p0 = __builtin_amdgcn_exp2f(shi[jn][0] - FIXED_M);
      float p1 = __builtin_amdgcn_exp2f(shi[jn][1] - FIXED_M);
      float p2 = __builtin_amdgcn_exp2f(shi[jn][2] - FIXED_M);
      float p3 = __builtin_amdgcn_exp2f(shi[jn][3] - FIXED_M);
      lsum_hi += (p0 + p1) + (p2 + p3);
      alignas(8) __hip_bfloat16 hp[4] = {
          __float2bfloat16(p0), __float2bfloat16(p1),
          __float2bfloat16(p2), __float2bfloat16(p3)};
      int wbyte = llo * 128 + ((((jn << 1) | (lhi >> 1)) ^ (llo & 7)) << 4) + ((lhi & 1) << 3);
      *reinterpret_cast<uint2*>(psw + wbyte) = *reinterpret_cast<const uint2*>(hp);
    }
    asm volatile("" ::: "memory");   // TBAA fence: pack-hi before read-hi
    {
      bf16x8 ap0 = *reinterpret_cast<const bf16x8*>(
          &Ps[wave][llo * 64 + ((lhi ^ (llo & 7)) << 3)]);
      bf16x8 ap1 = *reinterpret_cast<const bf16x8*>(
          &Ps[wave][llo * 64 + (((4 + lhi) ^ (llo & 7)) << 3)]);
      __builtin_amdgcn_s_setprio(1);
      #pragma unroll
      for (int jd = 0; jd < 4; ++jd) {
        o_hi[jd] = __builtin_amdgcn_mfma_f32_16x16x32_bf16(vf0[jd], ap0, o_hi[jd], 0, 0, 0);
        o_hi[jd] = __builtin_amdgcn_mfma_f32_16x16x32_bf16(vf1[jd], ap1, o_hi[jd], 0, 0, 0);
      }
      __builtin_amdgcn_s_setprio(0);
    }
    // ---- lo (guarded): softmax + pack + PV, reusing V-frags ----
    if (actlo) {
      asm volatile("" ::: "memory"); // fence: read-hi before pack-lo (same Ps)
      #pragma unroll
      for (int jn = 0; jn < 4; ++jn) {
        float p0 = __builtin_amdgcn_exp2f(slo[jn][0] - FIXED_M);
        float p1 = __builtin_amdgcn_exp2f(slo[jn][1] - FIXED_M);
        float p2 = __builtin_amdgcn_exp2f(slo[jn][2] - FIXED_M);
        float p3 = __builtin_amdgcn_exp2f(slo[jn][3] - FIXED_M);
        lsum_lo += (p0 + p1) + (p2 + p3);
        alignas(8) __hip_bfloat16 hp[4] = {
            __float2bfloat16(p0), __float2bfloat16(p1),
            __float2bfloat16(p2), __float2bfloat16(p3)};
        int wbyte = llo * 128 + ((((jn << 1) | (lhi >> 1)) ^ (llo & 7)) << 4) + ((lhi & 1) << 3);
        *reinterpret_cast<uint2*>(psw + wbyte) = *reinterpret_cast<const uint2*>(hp);
      }
      asm volatile("" ::: "memory"); // fence: pack-lo before read-lo
      bf16x8 ap0 = *reinterpret_cast<const bf16x8*>(
          &Ps[wave][llo * 64 + ((lhi ^ (llo & 7)) << 3)]);
      bf16x8 ap1 = *reinterpret_cast<const bf16x8*>(
          &Ps[wave][llo * 64 + (((4 + lhi) ^ (llo & 7)) << 3)]);
      __builtin_amdgcn_s_setprio(1);
      #pragma unroll
      for (int jd = 0; jd < 4; ++jd) {
        o_lo[jd] = __builtin_amdgcn_mfma_f32_16x16x32_bf16(vf0[jd], ap0, o_lo[jd], 0, 0, 0);
        o_lo[jd] = __builtin_amdgcn_mfma_f32_16x16x32_bf16(vf1[jd], ap1, o_lo[jd], 0, 0, 0);
      }
      __builtin_amdgcn_s_setprio(0);
    }
    __syncthreads();   // drains stage (vmcnt0) + guards 2-slot ring reuse
  }

  // row-sums (q lane-local): reduce across the 4 lhi lanes
  lsum_hi += __shfl_xor(lsum_hi, 16);
  lsum_hi += __shfl_xor(lsum_hi, 32);
  lsum_lo += __shfl_xor(lsum_lo, 16);
  lsum_lo += __shfl_xor(lsum_lo, 32);
  const float inv_hi = 1.0f / lsum_hi;
  const float inv_lo = 1.0f / lsum_lo;

  // epilogue: packed 8B stores for both q-tiles
  const int b = bh >> 4, h = bh & 15;
  __hip_bfloat16* yhi = Y + ((size_t)(b * T_ + myq_hi)) * DM_ + h * 64;
  __hip_bfloat16* ylo = Y + ((size_t)(b * T_ + myq_lo)) * DM_ + h * 64;
  #pragma unroll
  for (int jd = 0; jd < 4; ++jd) {
    alignas(8) __hip_bfloat16 t4[4];
    #pragma unroll
    for (int r = 0; r < 4; ++r) t4[r] = __float2bfloat16(o_hi[jd][r] * inv_hi);
    *reinterpret_cast<uint2*>(yhi + jd * 16 + lhi * 4) =
        *reinterpret_cast<const uint2*>(t4);
    alignas(8) __hip_bfloat16 t5[4];
    #pragma unroll
    for (int r = 0; r < 4; ++r) t5[r] = __float2bfloat16(o_lo[jd][r] * inv_lo);
    *reinterpret_cast<uint2*>(ylo + jd * 16 + lhi * 4) =
        *reinterpret_cast<const uint2*>(t5);
  }
}

// ---------------- launch ----------------
extern "C" void kernel_launch(void* const* d_in, const int* in_sizes, int n_in,
                              void* d_out, int out_size, void* d_ws, size_t ws_size,
                              hipStream_t stream) {
  const float* x     = (const float*)d_in[0];
  const float* w_qkv = (const float*)d_in[1];
  const float* w_out = (const float*)d_in[2];
  float* out = (float*)d_out;
  char* ws = (char*)d_ws;

  size_t off = 0;
  __hip_bfloat16* xb    = (__hip_bfloat16*)(ws + off); off += (size_t)M_ * DM_ * 2;      // 8 MiB
  __hip_bfloat16* wqkvT = (__hip_bfloat16*)(ws + off); off += (size_t)3 * DM_ * DM_ * 2; // 6 MiB
  __hip_bfloat16* woutT = (__hip_bfloat16*)(ws + off); off += (size_t)DM_ * DM_ * 2;     // 2 MiB
  __hip_bfloat16* q_ws  = (__hip_bfloat16*)(ws + off); off += (size_t)M_ * DM_ * 2;      // 8 MiB
  __hip_bfloat16* k_ws  = (__hip_bfloat16*)(ws + off); off += (size_t)M_ * DM_ * 2;      // 8 MiB
  __hip_bfloat16* vT    = (__hip_bfloat16*)(ws + off); off += (size_t)M_ * DM_ * 2;      // 8 MiB
  __hip_bfloat16* y_ws  = (__hip_bfloat16*)(ws + off); off += (size_t)M_ * DM_ * 2;      // 8 MiB
  (void)ws_size; (void)in_sizes; (void)n_in; (void)out_size;

  // fused prep: cvt x + transpose both weights (one launch)
  k_prep<<<8192, 256, 0, stream>>>(x, w_qkv, w_out, xb, wqkvT, woutT);

  // qkv projection (r14 core, 2D grid — best measured config)
  k_gemm_qkv<<<dim3(3 * DM_ / 128, M_ / 128), 256, 0, stream>>>(xb, wqkvT, q_ws, k_ws, vT);

  // causal flash attention (v13: dual q-tile per wave, swapped-operand)
  k_attn<<<dim3(16, BH_), 256, 0, stream>>>(q_ws, k_ws, vT, y_ws);

  // output projection (f32 out), 128x64 tiles -> 512 blocks
  k_gemm_out<<<dim3(DM_ / 64, M_ / 128), 256, 0, stream>>>(y_ws, woutT, out);
}

// Round 19
// 99.659 us; speedup vs baseline: 1.0554x; 1.0554x over previous
//
#include <hip/hip_runtime.h>
#include <hip/hip_bf16.h>
#include <stdint.h>

typedef __bf16 bf16x8 __attribute__((ext_vector_type(8)));
typedef float  f32x4  __attribute__((ext_vector_type(4)));

#define B_   2
#define T_   2048
#define H_   16
#define DH_  64
#define DM_  1024
#define BH_  (B_*H_)   // 32
#define M_   (B_*T_)   // 4096

#define QSCALE 0.18033688f   // 1/sqrt(64) * log2(e), folded into Q
#define FIXED_M 8.0f         // static softmax max (exp2 domain)

#define SBAR() __builtin_amdgcn_sched_barrier(0)

// ---- async global->LDS, 16B per lane; LDS dest must be wave-uniform base ----
static __device__ __forceinline__ void gload_lds16(const void* g, void* lds) {
  __builtin_amdgcn_global_load_lds(
      (const __attribute__((address_space(1))) void*)(uintptr_t)g,
      (__attribute__((address_space(3))) void*)(uint32_t)(uintptr_t)lds,
      16, 0, 0);
}

// ---------------- fused prep: cvt x + transpose both weights ----------------
__global__ void k_prep(const float* __restrict__ x, const float* __restrict__ wqkv,
                       const float* __restrict__ wout, __hip_bfloat16* __restrict__ xb,
                       __hip_bfloat16* __restrict__ wqkvT, __hip_bfloat16* __restrict__ woutT) {
  __shared__ float tile[32][33];
  const int bid = blockIdx.x, tid = threadIdx.x;
  if (bid < 4096) {
    int i = bid * 256 + tid;                       // 1M float4 = all of x
    float4 v = reinterpret_cast<const float4*>(x)[i];
    alignas(8) __hip_bfloat16 t[4] = {__float2bfloat16(v.x), __float2bfloat16(v.y),
                                      __float2bfloat16(v.z), __float2bfloat16(v.w)};
    reinterpret_cast<uint2*>(xb)[i] = *reinterpret_cast<const uint2*>(t);
    return;
  }
  const float* in; __hip_bfloat16* out; int K, N, n0, k0;
  if (bid < 7168) {
    int t = bid - 4096; in = wqkv; out = wqkvT; K = 1024; N = 3072;
    n0 = (t % 96) * 32; k0 = (t / 96) * 32;
  } else {
    int t = bid - 7168; in = wout; out = woutT; K = 1024; N = 1024;
    n0 = (t % 32) * 32; k0 = (t / 32) * 32;
  }
  int kl = tid >> 3, n4 = (tid & 7) * 4;
  float4 v = *reinterpret_cast<const float4*>(in + (size_t)(k0 + kl) * N + n0 + n4);
  tile[kl][n4 + 0] = v.x; tile[kl][n4 + 1] = v.y; tile[kl][n4 + 2] = v.z; tile[kl][n4 + 3] = v.w;
  __syncthreads();
  int nl = tid >> 3, k4 = (tid & 7) * 4;
  alignas(8) __hip_bfloat16 t[4];
  #pragma unroll
  for (int j = 0; j < 4; ++j) t[j] = __float2bfloat16(tile[k4 + j][nl]);
  *reinterpret_cast<uint2*>(out + (size_t)(n0 + nl) * K + k0 + k4) = *reinterpret_cast<const uint2*>(t);
}

// ---- pipelined bf16 GEMM core (B^T input), BK=32, 4 waves, 3-slot ring ----
// Counted-vmcnt: stage(ks+2) before compute(ks); vmcnt(LOADS) retires own
// stage(ks) only; ONE barrier per K-step. Chunk-XOR swizzle (G21 both-sides):
// stage reads global chunk (lane&3)^((lane>>3)&3) into linear LDS; fragment
// read uses chunk lhi^((llo>>1)&3) -> 2-way bank access (free).
template<int BM, int BN, int FM, int FN>
static __device__ __forceinline__ void gemm_core_pipe(
    const __hip_bfloat16* __restrict__ A, const __hip_bfloat16* __restrict__ BT,
    int K, int brow, int bcol, __hip_bfloat16* As, __hip_bfloat16* Bs,
    f32x4 acc[FM][FN]) {
  constexpr int WGN = BN / (16 * FN);
  constexpr int LOADS = BM / 64 + BN / 64;       // gloads per wave per stage
  constexpr int ASLOT = BM * 32, BSLOT = BN * 32;
  const int tid = threadIdx.x, wave = tid >> 6, lane = tid & 63;
  const int wr = wave / WGN, wc = wave % WGN;
  const int llo = lane & 15, lhi = lane >> 4;
  const int nk = K / 32;
  const int schunk = (lane & 3) ^ ((lane >> 3) & 3);
  auto stage = [&](int ks, int slot) {
    #pragma unroll
    for (int c = wave; c < BM / 16; c += 4)
      gload_lds16(A + (size_t)(brow + c * 16 + (lane >> 2)) * K + ks * 32 + schunk * 8,
                  As + slot * ASLOT + c * 512);
    #pragma unroll
    for (int c = wave; c < BN / 16; c += 4)
      gload_lds16(BT + (size_t)(bcol + c * 16 + (lane >> 2)) * K + ks * 32 + schunk * 8,
                  Bs + slot * BSLOT + c * 512);
  };
  stage(0, 0);
  stage(1, 1);
  const int rchunk = lhi ^ ((llo >> 1) & 3);     // swizzled read chunk
  for (int ks = 0; ks < nk; ++ks) {
    if constexpr (LOADS == 4)      asm volatile("s_waitcnt vmcnt(4)" ::: "memory");
    else if constexpr (LOADS == 3) asm volatile("s_waitcnt vmcnt(3)" ::: "memory");
    else                           asm volatile("s_waitcnt vmcnt(0)" ::: "memory");
    SBAR();
    __builtin_amdgcn_s_barrier();
    SBAR();
    const int s2 = (ks + 2 < nk) ? ks + 2 : nk - 1;  // clamped redundant tail
    stage(s2, (ks + 2) % 3);
    const __hip_bfloat16* Asl = As + (ks % 3) * ASLOT;
    const __hip_bfloat16* Bsl = Bs + (ks % 3) * BSLOT;
    bf16x8 a[FM], b[FN];
    #pragma unroll
    for (int i = 0; i < FM; ++i)
      a[i] = *reinterpret_cast<const bf16x8*>(
          Asl + (wr * FM * 16 + i * 16 + llo) * 32 + rchunk * 8);
    #pragma unroll
    for (int j = 0; j < FN; ++j)
      b[j] = *reinterpret_cast<const bf16x8*>(
          Bsl + (wc * FN * 16 + j * 16 + llo) * 32 + rchunk * 8);
    __builtin_amdgcn_s_setprio(1);
    #pragma unroll
    for (int i = 0; i < FM; ++i)
      #pragma unroll
      for (int j = 0; j < FN; ++j)
        acc[i][j] = __builtin_amdgcn_mfma_f32_16x16x32_bf16(a[i], b[j], acc[i][j], 0, 0, 0);
    __builtin_amdgcn_s_setprio(0);
  }
  asm volatile("s_waitcnt vmcnt(0)" ::: "memory");
}

// GEMM1: qkv = xb @ w_qkv (128x128 tile, r14-proven core, 2D grid).
// Epilogue: Q (pre-scaled) / K as [bh][t][dh]; V transposed to [bh][dh][t].
__global__ __launch_bounds__(256) void k_gemm_qkv(
    const __hip_bfloat16* __restrict__ A, const __hip_bfloat16* __restrict__ BT,
    __hip_bfloat16* __restrict__ q_ws, __hip_bfloat16* __restrict__ k_ws,
    __hip_bfloat16* __restrict__ vT) {
  alignas(16) __shared__ __hip_bfloat16 As[3 * 128 * 32];
  alignas(16) __shared__ __hip_bfloat16 Bs[3 * 128 * 32];
  f32x4 acc[4][4] = {};
  const int brow = blockIdx.y * 128, bcol = blockIdx.x * 128;
  gemm_core_pipe<128, 128, 4, 4>(A, BT, DM_, brow, bcol, As, Bs, acc);
  const int tid = threadIdx.x, wave = tid >> 6, lane = tid & 63;
  const int wr = wave >> 1, wc = wave & 1;
  const int llo = lane & 15, lhi = lane >> 4;
  #pragma unroll
  for (int i = 0; i < 4; ++i) {
    const int tbase = brow + wr * 64 + i * 16 + lhi * 4;  // 4 consecutive t
    const int b = tbase >> 11, t = tbase & 2047;
    #pragma unroll
    for (int j = 0; j < 4; ++j) {
      int n = bcol + wc * 64 + j * 16 + llo;
      int part = n >> 10, rem = n & 1023, hh = rem >> 6, dh = rem & 63;
      if (part == 2) {
        alignas(8) __hip_bfloat16 tv[4];
        #pragma unroll
        for (int r = 0; r < 4; ++r) tv[r] = __float2bfloat16(acc[i][j][r]);
        *reinterpret_cast<uint2*>(
            vT + (((size_t)(b * H_ + hh)) * DH_ + dh) * T_ + t) =
            *reinterpret_cast<const uint2*>(tv);
      } else {
        float sc = (part == 0) ? QSCALE : 1.0f;   // fold softmax scale into Q
        __hip_bfloat16* dst = (part == 0) ? q_ws : k_ws;
        #pragma unroll
        for (int r = 0; r < 4; ++r)
          dst[(((size_t)(b * H_ + hh)) * T_ + t + r) * DH_ + dh] =
              __float2bfloat16(acc[i][j][r] * sc);
      }
    }
  }
}

// GEMM2: out = y @ w_out (f32 output). 128x64 tile -> 512 blocks (2/CU).
__global__ __launch_bounds__(256) void k_gemm_out(
    const __hip_bfloat16* __restrict__ A, const __hip_bfloat16* __restrict__ BT,
    float* __restrict__ C) {
  alignas(16) __shared__ __hip_bfloat16 As[3 * 128 * 32];
  alignas(16) __shared__ __hip_bfloat16 Bs[3 * 64 * 32];
  f32x4 acc[4][2] = {};
  const int brow = blockIdx.y * 128, bcol = blockIdx.x * 64;
  gemm_core_pipe<128, 64, 4, 2>(A, BT, DM_, brow, bcol, As, Bs, acc);
  const int tid = threadIdx.x, wave = tid >> 6, lane = tid & 63;
  const int wr = wave >> 1, wc = wave & 1;
  const int llo = lane & 15, lhi = lane >> 4;
  #pragma unroll
  for (int i = 0; i < 4; ++i)
    #pragma unroll
    for (int j = 0; j < 2; ++j) {
      int n = bcol + wc * 32 + j * 16 + llo;
      #pragma unroll
      for (int r = 0; r < 4; ++r) {
        int m = brow + wr * 64 + i * 16 + lhi * 4 + r;
        C[(size_t)m * DM_ + n] = acc[i][j][r];
      }
    }
}

// ---------------- flash attention (causal), v12 (proven ~37 us) ----------
// v6 skeleton + swapped-operand MFMAs (S^T = mfma(K,Q), O^T = mfma(V,P)):
// lane holds q = llo fixed, 4 consecutive t' per (jn) -> P-pack is 4x 8B
// ds_write; row-sum lane-local. TBAA fence between P writes and P reads.
__global__ __launch_bounds__(512) void k_attn(
    const __hip_bfloat16* __restrict__ Q, const __hip_bfloat16* __restrict__ Kk,
    const __hip_bfloat16* __restrict__ VT, __hip_bfloat16* __restrict__ Y) {
  alignas(16) __shared__ __hip_bfloat16 Ks[4][64 * 64];
  alignas(16) __shared__ __hip_bfloat16 Vs[4][64 * 64];   // [dh][t'] swizzled
  alignas(16) __shared__ __hip_bfloat16 Ps[8][16 * 64];
  const int bh = blockIdx.y;
  const int p  = blockIdx.x;                 // 0..15
  const int tid = threadIdx.x, wave = tid >> 6, lane = tid & 63;
  const int llo = lane & 15, lhi = lane >> 4;
  const int qt   = (wave < 4) ? (31 - p) : p;
  const int myNt = qt + 1;
  const int ntA  = 32 - p;                   // block loop length (>= 17)
  const int q0 = qt * 64;
  const int qbase = q0 + (wave & 3) * 16;
  const int myq = qbase + llo;               // this lane's q row (swapped layout)

  const __hip_bfloat16* kb = Kk + (size_t)bh * T_ * DH_;
  const __hip_bfloat16* vb = VT + (size_t)bh * DH_ * T_;

  const int srow = lane >> 3;                // 0..7
  const int schunk = (lane & 7) ^ srow;      // involution XOR
  const int rb = wave * 8;

  bf16x8 aq[2];
  #pragma unroll
  for (int k0 = 0; k0 < 2; ++k0)
    aq[k0] = *reinterpret_cast<const bf16x8*>(
        Q + ((size_t)bh * T_ + myq) * DH_ + k0 * 32 + lhi * 8);

  float lsum = 0.f;                          // scalar row-sum (q = myq)
  f32x4 o[4] = {};

  // prologue: stage tiles 0,1 into buffers 0,1 (ntA >= 17 so both exist)
  gload_lds16(kb + (size_t)(rb + srow) * DH_ + schunk * 8, &Ks[0][rb * 64]);
  gload_lds16(vb + (size_t)(rb + srow) * T_ + schunk * 8, &Vs[0][rb * 64]);
  gload_lds16(kb + (size_t)(64 + rb + srow) * DH_ + schunk * 8, &Ks[1][rb * 64]);
  gload_lds16(vb + (size_t)(rb + srow) * T_ + 64 + schunk * 8, &Vs[1][rb * 64]);

  char* psw = reinterpret_cast<char*>(&Ps[wave][0]);

  for (int it = 0; it < ntA; ++it) {
    const int cur = it & 3;
    // stage tile it+2 (clamped tail keeps 2 loads/wave/iter: vmcnt(4) exact)
    {
      const int ts = (it + 2 < ntA) ? (it + 2) : (ntA - 1);
      const int bs = (it + 2) & 3;
      const int tn = ts * 64;
      gload_lds16(kb + (size_t)(tn + rb + srow) * DH_ + schunk * 8, &Ks[bs][rb * 64]);
      gload_lds16(vb + (size_t)(rb + srow) * T_ + tn + schunk * 8, &Vs[bs][rb * 64]);
    }
    asm volatile("s_waitcnt vmcnt(4)" ::: "memory");
    SBAR();
    __builtin_amdgcn_s_barrier();
    SBAR();

    if (it < myNt) {    // wave-uniform guard (waves 4-7 finish early)
      const __hip_bfloat16* ksb = Ks[cur];
      const __hip_bfloat16* vsb = Vs[cur];

      // S^T = K Q^T (swapped operands; addresses identical to v6)
      f32x4 s[4];
      __builtin_amdgcn_s_setprio(1);
      #pragma unroll
      for (int jn = 0; jn < 4; ++jn) {
        const __hip_bfloat16* krow = ksb + (jn * 16 + llo) * 64;
        bf16x8 b0 = *reinterpret_cast<const bf16x8*>(krow + ((lhi ^ (llo & 7)) << 3));
        bf16x8 b1 = *reinterpret_cast<const bf16x8*>(krow + (((4 + lhi) ^ (llo & 7)) << 3));
        f32x4 z = {};
        z = __builtin_amdgcn_mfma_f32_16x16x32_bf16(b0, aq[0], z, 0, 0, 0);
        z = __builtin_amdgcn_mfma_f32_16x16x32_bf16(b1, aq[1], z, 0, 0, 0);
        s[jn] = z;   // s[jn][r] = S[t' = it*64 + jn*16 + lhi*4 + r][q = myq]
      }
      __builtin_amdgcn_s_setprio(0);
      // causal mask only on the diagonal tile: t' > q -> -inf
      if (it == myNt - 1) {
        #pragma unroll
        for (int jn = 0; jn < 4; ++jn)
          #pragma unroll
          for (int r = 0; r < 4; ++r) {
            int tprime = q0 + jn * 16 + lhi * 4 + r;
            if (tprime > myq) s[jn][r] = -INFINITY;
          }
      }
      // static-max softmax + pack: 4 consecutive t' per (jn) -> one 8B write
      #pragma unroll
      for (int jn = 0; jn < 4; ++jn) {
        float p0 = __builtin_amdgcn_exp2f(s[jn][0] - FIXED_M);
        float p1 = __builtin_amdgcn_exp2f(s[jn][1] - FIXED_M);
        float p2 = __builtin_amdgcn_exp2f(s[jn][2] - FIXED_M);
        float p3 = __builtin_amdgcn_exp2f(s[jn][3] - FIXED_M);
        lsum += (p0 + p1) + (p2 + p3);
        alignas(8) __hip_bfloat16 hp[4] = {
            __float2bfloat16(p0), __float2bfloat16(p1),
            __float2bfloat16(p2), __float2bfloat16(p3)};
        // logical 16B chunk = jn*2 + (lhi>>1), swizzled ^(llo&7); 8B half = lhi&1
        int wbyte = llo * 128 + ((((jn << 1) | (lhi >> 1)) ^ (llo & 7)) << 4) + ((lhi & 1) << 3);
        *reinterpret_cast<uint2*>(psw + wbyte) = *reinterpret_cast<const uint2*>(hp);
      }
      // compiler fence: uint2 stores vs bf16x8 loads are TBAA-distinct; do
      // not let the P fragment reads get hoisted above the pack writes.
      asm volatile("" ::: "memory");
      // PV: O^T = mfma(A = V^T-frag, B = P-frag); addresses identical to v6
      bf16x8 ap0 = *reinterpret_cast<const bf16x8*>(
          &Ps[wave][llo * 64 + ((lhi ^ (llo & 7)) << 3)]);
      bf16x8 ap1 = *reinterpret_cast<const bf16x8*>(
          &Ps[wave][llo * 64 + (((4 + lhi) ^ (llo & 7)) << 3)]);
      __builtin_amdgcn_s_setprio(1);
      #pragma unroll
      for (int jd = 0; jd < 4; ++jd) {
        const __hip_bfloat16* vrow = vsb + (jd * 16 + llo) * 64;
        bf16x8 v0 = *reinterpret_cast<const bf16x8*>(vrow + ((lhi ^ (llo & 7)) << 3));
        bf16x8 v1 = *reinterpret_cast<const bf16x8*>(vrow + (((4 + lhi) ^ (llo & 7)) << 3));
        o[jd] = __builtin_amdgcn_mfma_f32_16x16x32_bf16(v0, ap0, o[jd], 0, 0, 0);
        o[jd] = __builtin_amdgcn_mfma_f32_16x16x32_bf16(v1, ap1, o[jd], 0, 0, 0);
      }
      __builtin_amdgcn_s_setprio(0);
    }
  }

  // row-sum: lanes {llo, llo+16, llo+32, llo+48} hold partials for q = myq
  lsum += __shfl_xor(lsum, 16);
  lsum += __shfl_xor(lsum, 32);
  const float inv = 1.0f / lsum;

  // epilogue: o[jd][r] = O[q = myq][dh = jd*16 + lhi*4 + r]; packed 8B stores
  const int b = bh >> 4, h = bh & 15;
  __hip_bfloat16* yrow = Y + ((size_t)(b * T_ + myq)) * DM_ + h * 64;
  #pragma unroll
  for (int jd = 0; jd < 4; ++jd) {
    alignas(8) __hip_bfloat16 t4[4];
    #pragma unroll
    for (int r = 0; r < 4; ++r) t4[r] = __float2bfloat16(o[jd][r] * inv);
    *reinterpret_cast<uint2*>(yrow + jd * 16 + lhi * 4) =
        *reinterpret_cast<const uint2*>(t4);
  }
}

// ---------------- launch ----------------
extern "C" void kernel_launch(void* const* d_in, const int* in_sizes, int n_in,
                              void* d_out, int out_size, void* d_ws, size_t ws_size,
                              hipStream_t stream) {
  const float* x     = (const float*)d_in[0];
  const float* w_qkv = (const float*)d_in[1];
  const float* w_out = (const float*)d_in[2];
  float* out = (float*)d_out;
  char* ws = (char*)d_ws;

  size_t off = 0;
  __hip_bfloat16* xb    = (__hip_bfloat16*)(ws + off); off += (size_t)M_ * DM_ * 2;      // 8 MiB
  __hip_bfloat16* wqkvT = (__hip_bfloat16*)(ws + off); off += (size_t)3 * DM_ * DM_ * 2; // 6 MiB
  __hip_bfloat16* woutT = (__hip_bfloat16*)(ws + off); off += (size_t)DM_ * DM_ * 2;     // 2 MiB
  __hip_bfloat16* q_ws  = (__hip_bfloat16*)(ws + off); off += (size_t)M_ * DM_ * 2;      // 8 MiB
  __hip_bfloat16* k_ws  = (__hip_bfloat16*)(ws + off); off += (size_t)M_ * DM_ * 2;      // 8 MiB
  __hip_bfloat16* vT    = (__hip_bfloat16*)(ws + off); off += (size_t)M_ * DM_ * 2;      // 8 MiB
  __hip_bfloat16* y_ws  = (__hip_bfloat16*)(ws + off); off += (size_t)M_ * DM_ * 2;      // 8 MiB
  (void)ws_size; (void)in_sizes; (void)n_in; (void)out_size;

  // fused prep: cvt x + transpose both weights (one launch)
  k_prep<<<8192, 256, 0, stream>>>(x, w_qkv, w_out, xb, wqkvT, woutT);

  // qkv projection (r14 core, 2D grid — best measured config)
  k_gemm_qkv<<<dim3(3 * DM_ / 128, M_ / 128), 256, 0, stream>>>(xb, wqkvT, q_ws, k_ws, vT);

  // causal flash attention (v12: swapped-operand MFMA)
  k_attn<<<dim3(T_ / 128, BH_), 512, 0, stream>>>(q_ws, k_ws, vT, y_ws);

  // output projection (f32 out), 128x64 tiles -> 512 blocks
  k_gemm_out<<<dim3(DM_ / 64, M_ / 128), 256, 0, stream>>>(y_ws, woutT, out);
}